// Round 3
// baseline (6261.740 us; speedup 1.0000x reference)
//
#include <hip/hip_runtime.h>
#include <hip/hip_fp16.h>
#include <math.h>

// Transformer_12970801234650 — full fused implementation.
// KEY STRUCTURE (discovered r2): _mha returns (bs,1,D); the residual add
// broadcasts (256,128)+(256,1,128) -> X[i,j,:] = x0[j,:] + attn0(x0[i,:]).
// Everything downstream is independent per i; layer-1 attention is a REAL
// 4-head seq-256 attention over j within each batch i. Output: (256,256) f32,
// out[i*256+j]. Layer-0 qw/kw are dead (softmax over len-1 = 1).
//
// K1 (prep): per row -> x0 (post-PE) and a0 (layer-0 attn out) into ws.
// K2 (batchk): block = batch i (256 blocks x 512 thr), X slice in LDS fp32
// (128KB, XOR swizzle d^(j&31) to avoid column bank conflicts), 32KB aux for
// FFN H-tile (f32 [256][32]) / per-head K,V (f16 [256][32] each). 160KB LDS.

#define SQRT_D 11.313708498984761f
#define PE_C   0.14391156831212787f   // ln(10000)/64
#define INV_SQRT_DK 0.17677669529663687f

#define XS(j,d) (((j) << 7) + ((d) ^ ((j) & 31)))

// ---------------- Kernel 1: prep (x0 and a0 per row) ----------------

struct P1 {
  const float* src; const int* t;
  const float* fc_w; const float* fc_b; const float* gc_w; const float* gc_b;
  const float* ln_w; const float* ln_b;
  const float* n1a; const float* n1b;
  const float* vw; const float* vb; const float* ow; const float* ob;
  float* x0; float* a0;
};

__device__ __forceinline__ float rowReduceSum(float v, volatile float* red, int d) {
#pragma unroll
  for (int off = 32; off > 0; off >>= 1) v += __shfl_xor(v, off, 64);
  if ((d & 63) == 0) red[d >> 6] = v;
  __syncthreads();
  float r = red[0] + red[1];
  __syncthreads();
  return r;
}

__device__ __forceinline__ float dot128s(const float* __restrict__ w,
                                         const float* __restrict__ xs) {
  const float4* __restrict__ w4 = (const float4*)w;
  const float4* __restrict__ x4 = (const float4*)xs;
  float a0 = 0.f, a1 = 0.f, a2 = 0.f, a3 = 0.f;
#pragma unroll
  for (int k = 0; k < 32; k += 4) {
    float4 xv0 = x4[k + 0], xv1 = x4[k + 1], xv2 = x4[k + 2], xv3 = x4[k + 3];
    float4 wv0 = w4[k + 0], wv1 = w4[k + 1], wv2 = w4[k + 2], wv3 = w4[k + 3];
    a0 = fmaf(wv0.w, xv0.w, fmaf(wv0.z, xv0.z, fmaf(wv0.y, xv0.y, fmaf(wv0.x, xv0.x, a0))));
    a1 = fmaf(wv1.w, xv1.w, fmaf(wv1.z, xv1.z, fmaf(wv1.y, xv1.y, fmaf(wv1.x, xv1.x, a1))));
    a2 = fmaf(wv2.w, xv2.w, fmaf(wv2.z, xv2.z, fmaf(wv2.y, xv2.y, fmaf(wv2.x, xv2.x, a2))));
    a3 = fmaf(wv3.w, xv3.w, fmaf(wv3.z, xv3.z, fmaf(wv3.y, xv3.y, fmaf(wv3.x, xv3.x, a3))));
  }
  return (a0 + a1) + (a2 + a3);
}

__global__ __launch_bounds__(256) void prep(P1 p) {
  __shared__ __align__(16) float s_src[2][16];
  __shared__ __align__(16) float s_x2[2][128];
  __shared__ __align__(16) float s_y[2][128];
  __shared__ float s_red[2][2];

  const int tid = threadIdx.x;
  const int rl  = tid >> 7;
  const int d   = tid & 127;
  const int row = blockIdx.x * 2 + rl;
  volatile float* red = s_red[rl];

  if (d < 14) s_src[rl][d + 1] = p.src[row * 14 + d];
  if (d == 14) { s_src[rl][0] = 0.f; s_src[rl][15] = 0.f; }
  __syncthreads();

  const float fw0 = p.fc_w[3 * d + 0], fw1 = p.fc_w[3 * d + 1], fw2 = p.fc_w[3 * d + 2];
  const float gw0 = p.gc_w[3 * d + 0], gw1 = p.gc_w[3 * d + 1], gw2 = p.gc_w[3 * d + 2];
  const float fb = p.fc_b[d], gb = p.gc_b[d];
  float g = 0.f;
#pragma unroll
  for (int m = 0; m < 14; ++m) {
    float xm1 = s_src[rl][m], x0v = s_src[rl][m + 1], xp1 = s_src[rl][m + 2];
    float f  = fmaf(fw2, xp1, fmaf(fw1, x0v, fmaf(fw0, xm1, fb)));
    float ga = fmaf(gw2, xp1, fmaf(gw1, x0v, fmaf(gw0, xm1, gb)));
    g = fmaf(f, 1.f / (1.f + expf(-ga)), g);
  }
  g *= (1.f / 14.f);

  // initial LayerNorm: biased var, eps inside sqrt
  float mu = rowReduceSum(g, red, d) * (1.f / 128.f);
  float cg = g - mu;
  float var = rowReduceSum(cg * cg, red, d) * (1.f / 128.f);
  float x = fmaf(p.ln_w[d], cg * rsqrtf(var + 1e-5f), p.ln_b[d]);

  // positional encoding
  const int tval = *p.t;
  {
    int i2 = d >> 1;
    float arg = (float)tval * expf((float)i2 * -PE_C);
    float pe = (d & 1) ? cosf(arg) : sinf(arg);
    x = fmaf(x, SQRT_D, pe);
  }
  p.x0[row * 128 + d] = x;

  // norm1 layer0 (ddof=1, eps on std)
  float mu1 = rowReduceSum(x, red, d) * (1.f / 128.f);
  float c1 = x - mu1;
  float v1 = rowReduceSum(c1 * c1, red, d) * (1.f / 127.f);
  s_x2[rl][d] = fmaf(p.n1a[d], c1 / (sqrtf(v1) + 1e-6f), p.n1b[d]);
  __syncthreads();

  // layer0 attention collapses: a0 = (x2@vw.T+vb)@ow.T+ob
  float y = p.vb[d] + dot128s(p.vw + d * 128, s_x2[rl]);
  s_y[rl][d] = y;
  __syncthreads();
  p.a0[row * 128 + d] = p.ob[d] + dot128s(p.ow + d * 128, s_y[rl]);
}

// ---------------- Kernel 2: per-batch mega-kernel ----------------

struct P2 {
  const float* x0; const float* a0;
  const float* qw; const float* qb; const float* kw; const float* kb;
  const float* vw; const float* vb; const float* ow; const float* ob;
  const float* n1a; const float* n1b; const float* n2a; const float* n2b;
  const float* w1; const float* b1; const float* w2; const float* b2;
  const float* fna; const float* fnb; const float* out_w; const float* out_b;
  float* out;
};

// load row j of sX into r[] and apply _norm (ddof=1, eps on std)
__device__ __forceinline__ void load_norm_row(const float* sX, int j,
    const float* __restrict__ aL, const float* __restrict__ bL, float* r) {
#pragma unroll
  for (int d = 0; d < 128; ++d) r[d] = sX[XS(j, d)];
  float mu = 0.f;
#pragma unroll
  for (int d = 0; d < 128; ++d) mu += r[d];
  mu *= (1.f / 128.f);
  float var = 0.f;
#pragma unroll
  for (int d = 0; d < 128; ++d) { float c = r[d] - mu; var += c * c; }
  var *= (1.f / 127.f);
  float inv = 1.f / (sqrtf(var) + 1e-6f);
#pragma unroll
  for (int d = 0; d < 128; ++d) r[d] = fmaf(aL[d] * inv, r[d] - mu, bL[d]);
}

// norm + FFN, residual accumulated into sX row jown. sH = f32 [256][32] tile.
__device__ __forceinline__ void ffn_block(float* sX, float* sH, float* r,
    int jown, int half,
    const float* __restrict__ naL, const float* __restrict__ nbL,
    const float* __restrict__ w1L, const float* __restrict__ b1L,
    const float* __restrict__ w2L, const float* __restrict__ b2L) {
  load_norm_row(sX, jown, naL, nbL, r);
  const int jx = jown & 31;
  for (int tt = 0; tt < 16; ++tt) {
    for (int u0 = 0; u0 < 16; ++u0) {
      int u = tt * 32 + half * 16 + u0;
      const float* wr = w1L + u * 128;
      float acc = b1L[u];
#pragma unroll
      for (int d = 0; d < 128; ++d) acc = fmaf(r[d], wr[d], acc);
      sH[jown * 32 + ((half * 16 + u0) ^ jx)] = fmaxf(acc, 0.f);
    }
    __syncthreads();
    for (int d0 = 0; d0 < 64; ++d0) {
      int d = half * 64 + d0;
      float s = (tt == 0) ? b2L[d] : 0.f;
      const float* w2r = w2L + d * 512 + tt * 32;
#pragma unroll
      for (int uu = 0; uu < 32; ++uu) s = fmaf(sH[jown * 32 + (uu ^ jx)], w2r[uu], s);
      sX[XS(jown, d)] += s;
    }
    __syncthreads();
  }
}

__global__ __launch_bounds__(512, 2) void batchk(P2 p) {
  __shared__ float sX[32768];                 // 128KB: X slice [256][128] f32, swizzled
  __shared__ __align__(16) float sAux[8192];  // 32KB: FFN H-tile f32 / attn K,V f16
  float* sH = sAux;
  __half* sK = (__half*)sAux;          // [256][32] f16 (16KB)
  __half* sV = ((__half*)sAux) + 8192; // [256][32] f16 (16KB)

  const int t    = threadIdx.x;
  const int i    = blockIdx.x;
  const int jown = t & 255;
  const int half = t >> 8;
  const int lane = t & 63;
  const int jq   = (t >> 6) * 32 + (lane >> 1);  // q-row (pair of lanes)
  const int kh   = t & 1;                        // pair half: even/odd k

  float r[128];

  // ---- Phase A: X[i,j,:] = x0[j] + a0[i]; then norm2_L0 + FFN0 residual ----
  {
    const float* x0r = p.x0 + jown * 128;
    const float* a0r = p.a0 + i * 128;
#pragma unroll
    for (int d = 0; d < 128; ++d) r[d] = x0r[d] + a0r[d];
    if (half == 0) {
#pragma unroll
      for (int d = 0; d < 128; ++d) sX[XS(jown, d)] = r[d];
    }
  }
  __syncthreads();
  ffn_block(sX, sH, r, jown, half, p.n2a, p.n2b, p.w1, p.b1, p.w2, p.b2);

  // ---- Phase B: layer-1 attention (4 heads, seq=256) ----
  const float* qw1 = p.qw + 16384; const float* qb1 = p.qb + 128;
  const float* kw1 = p.kw + 16384; const float* kb1 = p.kb + 128;
  const float* vw1 = p.vw + 16384; const float* vb1 = p.vb + 128;
  const float* ow1 = p.ow + 16384; const float* ob1 = p.ob + 128;
  const float* n1a1 = p.n1a + 128; const float* n1b1 = p.n1b + 128;

  float O0[32], O1[32];

  for (int h = 0; h < 4; ++h) {
    const int hb = h * 32;
    // K/V build from own row (x2 = norm1_L1(X1))
    load_norm_row(sX, jown, n1a1, n1b1, r);
    for (int c0 = 0; c0 < 16; ++c0) {
      int m = hb + half * 16 + c0;
      const float* kr = kw1 + m * 128;
      const float* vr = vw1 + m * 128;
      float kk = kb1[m], vv = vb1[m];
#pragma unroll
      for (int d = 0; d < 128; ++d) {
        kk = fmaf(r[d], kr[d], kk);
        vv = fmaf(r[d], vr[d], vv);
      }
      sK[jown * 32 + half * 16 + c0] = __float2half(kk);
      sV[jown * 32 + half * 16 + c0] = __float2half(vv);
    }
    __syncthreads();

    // q for row jq
    float q[32];
    load_norm_row(sX, jq, n1a1, n1b1, r);
    for (int c = 0; c < 32; ++c) {
      const float* qr = qw1 + (hb + c) * 128;
      float acc = qb1[hb + c];
#pragma unroll
      for (int d = 0; d < 128; ++d) acc = fmaf(r[d], qr[d], acc);
      q[c] = acc * INV_SQRT_DK;
    }

    // online softmax over k = kh, kh+2, ...
    float m_run = -1e30f, lsum = 0.f;
    float o[32];
#pragma unroll
    for (int c = 0; c < 32; ++c) o[c] = 0.f;
    for (int k = kh; k < 256; k += 2) {
      const __half2* krow = (const __half2*)(sK + k * 32);
      float s = 0.f;
#pragma unroll
      for (int cc = 0; cc < 16; ++cc) {
        float2 f = __half22float2(krow[cc]);
        s = fmaf(q[2 * cc], f.x, s);
        s = fmaf(q[2 * cc + 1], f.y, s);
      }
      float pcoef;
      if (s > m_run) {
        float corr = __expf(m_run - s);
        lsum *= corr;
#pragma unroll
        for (int c = 0; c < 32; ++c) o[c] *= corr;
        m_run = s; pcoef = 1.f;
      } else {
        pcoef = __expf(s - m_run);
      }
      lsum += pcoef;
      const __half2* vrow = (const __half2*)(sV + k * 32);
#pragma unroll
      for (int cc = 0; cc < 16; ++cc) {
        float2 f = __half22float2(vrow[cc]);
        o[2 * cc]     = fmaf(pcoef, f.x, o[2 * cc]);
        o[2 * cc + 1] = fmaf(pcoef, f.y, o[2 * cc + 1]);
      }
    }

    // merge lane pair (even k / odd k halves)
    float mo = __shfl_xor(m_run, 1);
    float lo = __shfl_xor(lsum, 1);
    float m2 = fmaxf(m_run, mo);
    float ea = __expf(m_run - m2), eb = __expf(mo - m2);
    float l2 = fmaf(lsum, ea, lo * eb);
    float invl = 1.f / l2;
    const bool keep = ((h >> 1) == kh);
#pragma unroll
    for (int c = 0; c < 32; ++c) {
      float oc = fmaf(o[c], ea, __shfl_xor(o[c], 1) * eb) * invl;
      if (keep) { if (h & 1) O1[c] = oc; else O0[c] = oc; }
    }
    __syncthreads();
  }

  // O-projection + residual: lane kh covers output cols m in [kh*64, kh*64+64)
  {
    const int mb = kh * 64;
    for (int d = 0; d < 128; ++d) {
      const float* owr = ow1 + d * 128 + mb;
      float part = 0.f;
#pragma unroll
      for (int c = 0; c < 32; ++c) part = fmaf(O0[c], owr[c], part);
#pragma unroll
      for (int c = 0; c < 32; ++c) part = fmaf(O1[c], owr[32 + c], part);
      float tot = part + __shfl_xor(part, 1);
      if (kh == 0) sX[XS(jq, d)] += tot + ob1[d];
    }
  }
  __syncthreads();

  // ---- Phase C: norm2_L1 + FFN1 residual ----
  ffn_block(sX, sH, r, jown, half,
            p.n2a + 128, p.n2b + 128, p.w1 + 65536, p.b1 + 512,
            p.w2 + 65536, p.b2 + 128);

  // ---- Phase D: final norm + output projection ----
  load_norm_row(sX, jown, p.fna, p.fnb, r);
  float os = 0.f;
#pragma unroll
  for (int d = 0; d < 128; ++d) os = fmaf(r[d], p.out_w[d], os);
  if (half == 0) p.out[i * 256 + jown] = os + p.out_b[0];
}

// ---------------- host ----------------

extern "C" void kernel_launch(void* const* d_in, const int* in_sizes, int n_in,
                              void* d_out, int out_size, void* d_ws, size_t ws_size,
                              hipStream_t stream) {
  float* x0 = (float*)d_ws;                    // [256][128]
  float* a0 = (float*)d_ws + 32768;            // [256][128]

  P1 p1;
  p1.src  = (const float*)d_in[0];
  p1.t    = (const int*)  d_in[1];
  p1.fc_w = (const float*)d_in[2];  p1.fc_b = (const float*)d_in[3];
  p1.gc_w = (const float*)d_in[4];  p1.gc_b = (const float*)d_in[5];
  p1.ln_w = (const float*)d_in[6];  p1.ln_b = (const float*)d_in[7];
  p1.n1a  = (const float*)d_in[16]; p1.n1b  = (const float*)d_in[17];
  p1.vw   = (const float*)d_in[12]; p1.vb   = (const float*)d_in[13];
  p1.ow   = (const float*)d_in[14]; p1.ob   = (const float*)d_in[15];
  p1.x0 = x0; p1.a0 = a0;
  prep<<<dim3(128), dim3(256), 0, stream>>>(p1);

  P2 p2;
  p2.x0 = x0; p2.a0 = a0;
  p2.qw = (const float*)d_in[8];  p2.qb = (const float*)d_in[9];
  p2.kw = (const float*)d_in[10]; p2.kb = (const float*)d_in[11];
  p2.vw = (const float*)d_in[12]; p2.vb = (const float*)d_in[13];
  p2.ow = (const float*)d_in[14]; p2.ob = (const float*)d_in[15];
  p2.n1a = (const float*)d_in[16]; p2.n1b = (const float*)d_in[17];
  p2.n2a = (const float*)d_in[18]; p2.n2b = (const float*)d_in[19];
  p2.w1 = (const float*)d_in[20]; p2.b1 = (const float*)d_in[21];
  p2.w2 = (const float*)d_in[22]; p2.b2 = (const float*)d_in[23];
  p2.fna = (const float*)d_in[24]; p2.fnb = (const float*)d_in[25];
  p2.out_w = (const float*)d_in[26]; p2.out_b = (const float*)d_in[27];
  p2.out = (float*)d_out;
  batchk<<<dim3(256), dim3(512), 0, stream>>>(p2);
}

// Round 4
// 2343.452 us; speedup vs baseline: 2.6720x; 2.6720x over previous
//
#include <hip/hip_runtime.h>
#include <math.h>

// Transformer_12970801234650 r4: spill-free fp32/f16-dot2 megakernel.
// Structure (verified r3, passed): X[i,j,:] = x0[j] + a0[i]; per batch i:
// FFN0 -> real 4-head seq-256 attention (layer1) -> FFN1 -> final norm -> out.
// r3 bottleneck: 8 GB/dispatch scratch spill traffic (r[128]+q/o arrays @ 128
// VGPR cap). r4: no big per-thread arrays; f16x2 dot2 math; residuals flushed
// to LDS chunk-wise so only static-indexed small arrays live in regs.

#define SQRT_D 11.313708498984761f
#define PE_C   0.14391156831212787f   // ln(10000)/64
#define INV_SQRT_DK 0.17677669529663687f
#define XS(j,d) (((j) << 7) + ((d) ^ ((j) & 31)))

typedef _Float16 f16x2 __attribute__((ext_vector_type(2)));

__device__ __forceinline__ f16x2 mk2(float a, float b) {
  f16x2 v; v.x = (_Float16)a; v.y = (_Float16)b; return v;
}

#if defined(__has_builtin)
#if __has_builtin(__builtin_amdgcn_fdot2)
#define FDOT2(a, b, c) __builtin_amdgcn_fdot2((a), (b), (c), false)
#endif
#endif
#ifndef FDOT2
__device__ __forceinline__ float fdot2_fb(f16x2 a, f16x2 b, float c) {
  return fmaf((float)a.y, (float)b.y, fmaf((float)a.x, (float)b.x, c));
}
#define FDOT2(a, b, c) fdot2_fb((a), (b), (c))
#endif

// ---------------- K0: weight f32 -> f16 conversion ----------------
struct P0 { const float *qw, *kw, *vw, *ow, *w1, *w2; _Float16* dst; };

__global__ __launch_bounds__(256) void convf16(P0 p) {
  const int idx = blockIdx.x * 256 + threadIdx.x;
  float v;
  if      (idx <  32768) v = p.qw[idx];
  else if (idx <  65536) v = p.kw[idx -  32768];
  else if (idx <  98304) v = p.vw[idx -  65536];
  else if (idx < 131072) v = p.ow[idx -  98304];
  else if (idx < 262144) v = p.w1[idx - 131072];
  else                   v = p.w2[idx - 262144];
  p.dst[idx] = (_Float16)v;
}

// ---------------- K1: prep (x0 and a0 per row) — verified r3 ----------------
struct P1 {
  const float* src; const int* t;
  const float* fc_w; const float* fc_b; const float* gc_w; const float* gc_b;
  const float* ln_w; const float* ln_b;
  const float* n1a; const float* n1b;
  const float* vw; const float* vb; const float* ow; const float* ob;
  float* x0; float* a0;
};

__device__ __forceinline__ float rowReduceSum(float v, volatile float* red, int d) {
#pragma unroll
  for (int off = 32; off > 0; off >>= 1) v += __shfl_xor(v, off, 64);
  if ((d & 63) == 0) red[d >> 6] = v;
  __syncthreads();
  float r = red[0] + red[1];
  __syncthreads();
  return r;
}

__device__ __forceinline__ float dot128s(const float* __restrict__ w,
                                         const float* __restrict__ xs) {
  const float4* __restrict__ w4 = (const float4*)w;
  const float4* __restrict__ x4 = (const float4*)xs;
  float a0 = 0.f, a1 = 0.f, a2 = 0.f, a3 = 0.f;
#pragma unroll
  for (int k = 0; k < 32; k += 4) {
    float4 xv0 = x4[k + 0], xv1 = x4[k + 1], xv2 = x4[k + 2], xv3 = x4[k + 3];
    float4 wv0 = w4[k + 0], wv1 = w4[k + 1], wv2 = w4[k + 2], wv3 = w4[k + 3];
    a0 = fmaf(wv0.w, xv0.w, fmaf(wv0.z, xv0.z, fmaf(wv0.y, xv0.y, fmaf(wv0.x, xv0.x, a0))));
    a1 = fmaf(wv1.w, xv1.w, fmaf(wv1.z, xv1.z, fmaf(wv1.y, xv1.y, fmaf(wv1.x, xv1.x, a1))));
    a2 = fmaf(wv2.w, xv2.w, fmaf(wv2.z, xv2.z, fmaf(wv2.y, xv2.y, fmaf(wv2.x, xv2.x, a2))));
    a3 = fmaf(wv3.w, xv3.w, fmaf(wv3.z, xv3.z, fmaf(wv3.y, xv3.y, fmaf(wv3.x, xv3.x, a3))));
  }
  return (a0 + a1) + (a2 + a3);
}

__global__ __launch_bounds__(256) void prep(P1 p) {
  __shared__ __align__(16) float s_src[2][16];
  __shared__ __align__(16) float s_x2[2][128];
  __shared__ __align__(16) float s_y[2][128];
  __shared__ float s_red[2][2];

  const int tid = threadIdx.x;
  const int rl  = tid >> 7;
  const int d   = tid & 127;
  const int row = blockIdx.x * 2 + rl;
  volatile float* red = s_red[rl];

  if (d < 14) s_src[rl][d + 1] = p.src[row * 14 + d];
  if (d == 14) { s_src[rl][0] = 0.f; s_src[rl][15] = 0.f; }
  __syncthreads();

  const float fw0 = p.fc_w[3*d+0], fw1 = p.fc_w[3*d+1], fw2 = p.fc_w[3*d+2];
  const float gw0 = p.gc_w[3*d+0], gw1 = p.gc_w[3*d+1], gw2 = p.gc_w[3*d+2];
  const float fb = p.fc_b[d], gb = p.gc_b[d];
  float g = 0.f;
#pragma unroll
  for (int m = 0; m < 14; ++m) {
    float xm1 = s_src[rl][m], x0v = s_src[rl][m+1], xp1 = s_src[rl][m+2];
    float f  = fmaf(fw2, xp1, fmaf(fw1, x0v, fmaf(fw0, xm1, fb)));
    float ga = fmaf(gw2, xp1, fmaf(gw1, x0v, fmaf(gw0, xm1, gb)));
    g = fmaf(f, 1.f / (1.f + expf(-ga)), g);
  }
  g *= (1.f / 14.f);

  float mu = rowReduceSum(g, red, d) * (1.f / 128.f);
  float cg = g - mu;
  float var = rowReduceSum(cg * cg, red, d) * (1.f / 128.f);
  float x = fmaf(p.ln_w[d], cg * rsqrtf(var + 1e-5f), p.ln_b[d]);

  const int tval = *p.t;
  {
    int i2 = d >> 1;
    float arg = (float)tval * expf((float)i2 * -PE_C);
    float pe = (d & 1) ? cosf(arg) : sinf(arg);
    x = fmaf(x, SQRT_D, pe);
  }
  p.x0[row * 128 + d] = x;

  float mu1 = rowReduceSum(x, red, d) * (1.f / 128.f);
  float c1 = x - mu1;
  float v1 = rowReduceSum(c1 * c1, red, d) * (1.f / 127.f);
  s_x2[rl][d] = fmaf(p.n1a[d], c1 / (sqrtf(v1) + 1e-6f), p.n1b[d]);
  __syncthreads();

  float y = p.vb[d] + dot128s(p.vw + d * 128, s_x2[rl]);
  s_y[rl][d] = y;
  __syncthreads();
  p.a0[row * 128 + d] = p.ob[d] + dot128s(p.ow + d * 128, s_y[rl]);
}

// ---------------- K2: per-batch megakernel ----------------
struct P2 {
  const float* x0; const float* a0;
  const f16x2 *qw16, *kw16, *vw16, *ow16, *w116, *w216;
  const float *qb, *kb, *vb, *ob;
  const float *n1a, *n1b, *n2a, *n2b;
  const float *b1, *b2;
  const float *fna, *fnb, *out_w, *out_b;
  float* out;
};

// norm (_norm: ddof=1, eps on std) of sX row j -> packed f16x2[64]
__device__ __forceinline__ void norm_row_to_h2(const float* sX, int j,
    const float* __restrict__ na, const float* __restrict__ nb, f16x2* out) {
  float mu = 0.f;
#pragma unroll 16
  for (int d = 0; d < 128; ++d) mu += sX[XS(j, d)];
  mu *= (1.f / 128.f);
  float var = 0.f;
#pragma unroll 16
  for (int d = 0; d < 128; ++d) { float c = sX[XS(j, d)] - mu; var = fmaf(c, c, var); }
  const float inv = 1.f / (sqrtf(var * (1.f / 127.f)) + 1e-6f);
#pragma unroll
  for (int d2 = 0; d2 < 64; ++d2) {
    float a = fmaf(na[2*d2]   * inv, sX[XS(j, 2*d2)]   - mu, nb[2*d2]);
    float b = fmaf(na[2*d2+1] * inv, sX[XS(j, 2*d2+1)] - mu, nb[2*d2+1]);
    out[d2] = mk2(a, b);
  }
}

// norm2 + FFN (relu(x2@w1^T+b1)@w2^T+b2), residual flushed into sX chunk-wise
__device__ __forceinline__ void ffn_phase(float* sX, f16x2* sAux, int t,
    const float* __restrict__ na, const float* __restrict__ nb,
    const f16x2* __restrict__ w1, const float* __restrict__ b1,
    const f16x2* __restrict__ w2, const float* __restrict__ b2) {
  const int j = t & 255, half = t >> 8;
  const int dh = half * 64;
  f16x2 x2h[64];
  norm_row_to_h2(sX, j, na, nb, x2h);
  for (int c = 0; c < 8; ++c) {            // u-chunks of 64
    // gen 32 H values: u = c*64 + half*32 + u0
    for (int u0 = 0; u0 < 32; u0 += 2) {
      const int u = c * 64 + half * 32 + u0;
      float h0 = b1[u], h1 = b1[u + 1];
      const f16x2* __restrict__ r0 = w1 + u * 64;
      const f16x2* __restrict__ r1 = r0 + 64;
#pragma unroll
      for (int k = 0; k < 64; ++k) { h0 = FDOT2(x2h[k], r0[k], h0); h1 = FDOT2(x2h[k], r1[k], h1); }
      const int u2 = half * 16 + (u0 >> 1);
      sAux[j * 32 + (u2 ^ (j & 31))] = mk2(fmaxf(h0, 0.f), fmaxf(h1, 0.f));
    }
    __syncthreads();
    // consume: own d-half, accumulate into sX
    f16x2 hrow[32];
#pragma unroll
    for (int u2 = 0; u2 < 32; ++u2) hrow[u2] = sAux[j * 32 + (u2 ^ (j & 31))];
    for (int dg = 0; dg < 8; ++dg) {
      float aa[8];
#pragma unroll
      for (int dd = 0; dd < 8; ++dd) {
        const int d = dh + dg * 8 + dd;
        float a = (c == 0) ? b2[d] : 0.f;
        const f16x2* __restrict__ w2r = w2 + d * 256 + c * 32;
#pragma unroll
        for (int u2 = 0; u2 < 32; ++u2) a = FDOT2(hrow[u2], w2r[u2], a);
        aa[dd] = a;
      }
#pragma unroll
      for (int dd = 0; dd < 8; ++dd) sX[XS(j, dh + dg * 8 + dd)] += aa[dd];
    }
    __syncthreads();
  }
}

__device__ __forceinline__ void attn_phase(float* sX, f16x2* sAux, int t, const P2& p) {
  const int jg = t & 255, ghalf = t >> 8;   // gen mapping: row jg, K- or V-half
  const int jq = t >> 1,  kh = t & 1;       // flash mapping: row jq, k'-parity
  const float* __restrict__ n1a = p.n1a + 128;
  const float* __restrict__ n1b = p.n1b + 128;
  const float* __restrict__ qb = p.qb + 128;
  const float* __restrict__ kb = p.kb + 128;
  const float* __restrict__ vb = p.vb + 128;
  const float* __restrict__ ob = p.ob + 128;
  const f16x2* __restrict__ qw = p.qw16 + 8192;  // layer-1 slice
  const f16x2* __restrict__ kw = p.kw16 + 8192;
  const f16x2* __restrict__ vw = p.vw16 + 8192;
  const f16x2* __restrict__ ow = p.ow16 + 8192;

  f16x2 x2g[64], x2q[64];                   // norm1(X2) for both row mappings
  norm_row_to_h2(sX, jg, n1a, n1b, x2g);
  norm_row_to_h2(sX, jq, n1a, n1b, x2q);

  const f16x2* __restrict__ wg = ghalf ? vw : kw;
  const float* __restrict__ bg = ghalf ? vb : kb;
  const int lbase = ghalf ? 4096 : 0;       // sK @ 0, sV @ 4096 (f16x2 units)

  for (int h = 0; h < 4; ++h) {
    const int hb = h * 32;
    // ---- gen K (ghalf=0) / V (ghalf=1) for row jg ----
    for (int c2 = 0; c2 < 16; ++c2) {
      const int c = hb + 2 * c2;
      float o0 = bg[c], o1 = bg[c + 1];
      const f16x2* __restrict__ r0 = wg + c * 64;
      const f16x2* __restrict__ r1 = r0 + 64;
#pragma unroll
      for (int k = 0; k < 64; ++k) { o0 = FDOT2(x2g[k], r0[k], o0); o1 = FDOT2(x2g[k], r1[k], o1); }
      sAux[lbase + jg * 16 + (c2 ^ (jg & 15))] = mk2(o0, o1);
    }
    __syncthreads();
    // ---- q projection for row jq (scale folded in) ----
    f16x2 q2[16];
    for (int c2 = 0; c2 < 16; ++c2) {
      const int c = hb + 2 * c2;
      float o0 = qb[c], o1 = qb[c + 1];
      const f16x2* __restrict__ r0 = qw + c * 64;
      const f16x2* __restrict__ r1 = r0 + 64;
#pragma unroll
      for (int k = 0; k < 64; ++k) { o0 = FDOT2(x2q[k], r0[k], o0); o1 = FDOT2(x2q[k], r1[k], o1); }
      q2[c2] = mk2(o0 * INV_SQRT_DK, o1 * INV_SQRT_DK);
    }
    // ---- online-softmax flash over k' = kh, kh+2, ... ----
    float m_run = -1e30f, lsum = 0.f;
    float o[32];
#pragma unroll
    for (int c = 0; c < 32; ++c) o[c] = 0.f;
    for (int k2 = 0; k2 < 128; ++k2) {
      const int kk = 2 * k2 + kh;
      const f16x2* __restrict__ krow = sAux + kk * 16;
      float s = 0.f;
#pragma unroll
      for (int c2 = 0; c2 < 16; ++c2) s = FDOT2(q2[c2], krow[c2 ^ (kk & 15)], s);
      float pc;
      if (s > m_run) {
        const float corr = __expf(m_run - s);
        lsum *= corr;
#pragma unroll
        for (int c = 0; c < 32; ++c) o[c] *= corr;
        m_run = s; pc = 1.f;
      } else {
        pc = __expf(s - m_run);
      }
      lsum += pc;
      const f16x2* __restrict__ vrow = sAux + 4096 + kk * 16;
#pragma unroll
      for (int c2 = 0; c2 < 16; ++c2) {
        const f16x2 vv = vrow[c2 ^ (kk & 15)];
        o[2*c2]   = fmaf(pc, (float)vv.x, o[2*c2]);
        o[2*c2+1] = fmaf(pc, (float)vv.y, o[2*c2+1]);
      }
    }
    // ---- merge lane pair (even/odd k') ----
    const float mo = __shfl_xor(m_run, 1);
    const float lo = __shfl_xor(lsum, 1);
    const float m2 = fmaxf(m_run, mo);
    const float ea = __expf(m_run - m2), eb = __expf(mo - m2);
    const float linv = 1.f / fmaf(lsum, ea, lo * eb);
    f16x2 oh[16];
#pragma unroll
    for (int c2 = 0; c2 < 16; ++c2) {
      const float p0 = fmaf(o[2*c2],   ea, __shfl_xor(o[2*c2],   1) * eb) * linv;
      const float p1 = fmaf(o[2*c2+1], ea, __shfl_xor(o[2*c2+1], 1) * eb) * linv;
      oh[c2] = mk2(p0, p1);
    }
    // ---- O-projection partial residual into sX (own d-half) ----
    const int db = kh * 64;
    for (int dg = 0; dg < 8; ++dg) {
      float aa[8];
#pragma unroll
      for (int dd = 0; dd < 8; ++dd) {
        const int d = db + dg * 8 + dd;
        const f16x2* __restrict__ owr = ow + d * 64 + (hb >> 1);
        float a = (h == 0) ? ob[d] : 0.f;
#pragma unroll
        for (int c2 = 0; c2 < 16; ++c2) a = FDOT2(oh[c2], owr[c2], a);
        aa[dd] = a;
      }
#pragma unroll
      for (int dd = 0; dd < 8; ++dd) sX[XS(jq, db + dg * 8 + dd)] += aa[dd];
    }
    __syncthreads();
  }
}

__global__ __launch_bounds__(512, 2) void batchk(P2 p) {
  __shared__ float sX[32768];      // 128 KB residual stream, XS-swizzled
  __shared__ f16x2 sAux[8192];     // 32 KB: FFN H-chunk | attn K,V
  const int t = threadIdx.x;
  const int i = blockIdx.x;

  // Phase A: X[i,j,:] = x0[j] + a0[i]
  for (int k = 0; k < 64; ++k) {
    const int idx = t + 512 * k;
    const int j = idx >> 7, d = idx & 127;
    sX[XS(j, d)] = p.x0[idx] + p.a0[i * 128 + d];
  }
  __syncthreads();

  ffn_phase(sX, sAux, t, p.n2a, p.n2b, p.w116, p.b1, p.w216, p.b2);
  attn_phase(sX, sAux, t, p);
  ffn_phase(sX, sAux, t, p.n2a + 128, p.n2b + 128,
            p.w116 + 32768, p.b1 + 512, p.w216 + 32768, p.b2 + 128);

  // Phase D: final norm + output projection
  {
    const int j = t >> 1, hd = t & 1;
    float mu = 0.f, var = 0.f;
#pragma unroll 16
    for (int d = 0; d < 128; ++d) mu += sX[XS(j, d)];
    mu *= (1.f / 128.f);
#pragma unroll 16
    for (int d = 0; d < 128; ++d) { float c = sX[XS(j, d)] - mu; var = fmaf(c, c, var); }
    const float inv = 1.f / (sqrtf(var * (1.f / 127.f)) + 1e-6f);
    float os = 0.f;
    for (int d0 = 0; d0 < 64; ++d0) {
      const int d = hd * 64 + d0;
      const float xv = fmaf(p.fna[d] * inv, sX[XS(j, d)] - mu, p.fnb[d]);
      os = fmaf(xv, p.out_w[d], os);
    }
    os += __shfl_xor(os, 1);
    if (hd == 0) p.out[i * 256 + j] = os + p.out_b[0];
  }
}

// ---------------- host ----------------
extern "C" void kernel_launch(void* const* d_in, const int* in_sizes, int n_in,
                              void* d_out, int out_size, void* d_ws, size_t ws_size,
                              hipStream_t stream) {
  float* x0 = (float*)d_ws;                       // 32768 f32
  float* a0 = x0 + 32768;                         // 32768 f32
  _Float16* W16 = (_Float16*)((char*)d_ws + 262144);  // 393216 halves

  P0 p0;
  p0.qw = (const float*)d_in[8];  p0.kw = (const float*)d_in[10];
  p0.vw = (const float*)d_in[12]; p0.ow = (const float*)d_in[14];
  p0.w1 = (const float*)d_in[20]; p0.w2 = (const float*)d_in[22];
  p0.dst = W16;
  convf16<<<dim3(1536), dim3(256), 0, stream>>>(p0);

  P1 p1;
  p1.src  = (const float*)d_in[0];
  p1.t    = (const int*)  d_in[1];
  p1.fc_w = (const float*)d_in[2];  p1.fc_b = (const float*)d_in[3];
  p1.gc_w = (const float*)d_in[4];  p1.gc_b = (const float*)d_in[5];
  p1.ln_w = (const float*)d_in[6];  p1.ln_b = (const float*)d_in[7];
  p1.n1a  = (const float*)d_in[16]; p1.n1b  = (const float*)d_in[17];
  p1.vw   = (const float*)d_in[12]; p1.vb   = (const float*)d_in[13];
  p1.ow   = (const float*)d_in[14]; p1.ob   = (const float*)d_in[15];
  p1.x0 = x0; p1.a0 = a0;
  prep<<<dim3(128), dim3(256), 0, stream>>>(p1);

  P2 p2;
  p2.x0 = x0; p2.a0 = a0;
  p2.qw16 = (const f16x2*)W16;
  p2.kw16 = p2.qw16 + 16384;
  p2.vw16 = p2.kw16 + 16384;
  p2.ow16 = p2.vw16 + 16384;
  p2.w116 = p2.ow16 + 16384;     // 65536 f16x2
  p2.w216 = p2.w116 + 65536;
  p2.qb = (const float*)d_in[9];  p2.kb = (const float*)d_in[11];
  p2.vb = (const float*)d_in[13]; p2.ob = (const float*)d_in[15];
  p2.n1a = (const float*)d_in[16]; p2.n1b = (const float*)d_in[17];
  p2.n2a = (const float*)d_in[18]; p2.n2b = (const float*)d_in[19];
  p2.b1 = (const float*)d_in[21];  p2.b2 = (const float*)d_in[23];
  p2.fna = (const float*)d_in[24]; p2.fnb = (const float*)d_in[25];
  p2.out_w = (const float*)d_in[26]; p2.out_b = (const float*)d_in[27];
  p2.out = (float*)d_out;
  batchk<<<dim3(256), dim3(512), 0, stream>>>(p2);
}

// Round 5
// 2149.996 us; speedup vs baseline: 2.9124x; 1.0900x over previous
//
#include <hip/hip_runtime.h>
#include <math.h>

// Transformer_12970801234650 r5: de-spilled f16-dot2 megakernel.
// r4 post-mortem: WRITE_SIZE 816MB = scratch spills (VGPR capped at 128 by
// __launch_bounds__(512,2); attn kept x2g[64]+x2q[64] f16x2 live = 128 VGPR
// alone). r5: __launch_bounds__(512,1) (cap >= 256 VGPR) + hoist all-4-head
// q fragments so only ONE normalized row (x2g) stays live in the head loop.
// Structure (verified r3/r4): X[i,j,:] = x0[j] + a0[i]; per batch i:
// FFN0 -> 4-head seq-256 attention (layer1 weights) -> FFN1 -> norm -> out.

#define SQRT_D 11.313708498984761f
#define PE_C   0.14391156831212787f   // ln(10000)/64
#define INV_SQRT_DK 0.17677669529663687f
#define XS(j,d) (((j) << 7) + ((d) ^ ((j) & 31)))

typedef _Float16 f16x2 __attribute__((ext_vector_type(2)));

__device__ __forceinline__ f16x2 mk2(float a, float b) {
  f16x2 v; v.x = (_Float16)a; v.y = (_Float16)b; return v;
}

#if defined(__has_builtin)
#if __has_builtin(__builtin_amdgcn_fdot2)
#define FDOT2(a, b, c) __builtin_amdgcn_fdot2((a), (b), (c), false)
#endif
#endif
#ifndef FDOT2
__device__ __forceinline__ float fdot2_fb(f16x2 a, f16x2 b, float c) {
  return fmaf((float)a.y, (float)b.y, fmaf((float)a.x, (float)b.x, c));
}
#define FDOT2(a, b, c) fdot2_fb((a), (b), (c))
#endif

// ---------------- K0: weight f32 -> f16 conversion ----------------
struct P0 { const float *qw, *kw, *vw, *ow, *w1, *w2; _Float16* dst; };

__global__ __launch_bounds__(256) void convf16(P0 p) {
  const int idx = blockIdx.x * 256 + threadIdx.x;
  float v;
  if      (idx <  32768) v = p.qw[idx];
  else if (idx <  65536) v = p.kw[idx -  32768];
  else if (idx <  98304) v = p.vw[idx -  65536];
  else if (idx < 131072) v = p.ow[idx -  98304];
  else if (idx < 262144) v = p.w1[idx - 131072];
  else                   v = p.w2[idx - 262144];
  p.dst[idx] = (_Float16)v;
}

// ---------------- K1: prep (x0 and a0 per row) — verified r3 ----------------
struct P1 {
  const float* src; const int* t;
  const float* fc_w; const float* fc_b; const float* gc_w; const float* gc_b;
  const float* ln_w; const float* ln_b;
  const float* n1a; const float* n1b;
  const float* vw; const float* vb; const float* ow; const float* ob;
  float* x0; float* a0;
};

__device__ __forceinline__ float rowReduceSum(float v, volatile float* red, int d) {
#pragma unroll
  for (int off = 32; off > 0; off >>= 1) v += __shfl_xor(v, off, 64);
  if ((d & 63) == 0) red[d >> 6] = v;
  __syncthreads();
  float r = red[0] + red[1];
  __syncthreads();
  return r;
}

__device__ __forceinline__ float dot128s(const float* __restrict__ w,
                                         const float* __restrict__ xs) {
  const float4* __restrict__ w4 = (const float4*)w;
  const float4* __restrict__ x4 = (const float4*)xs;
  float a0 = 0.f, a1 = 0.f, a2 = 0.f, a3 = 0.f;
#pragma unroll
  for (int k = 0; k < 32; k += 4) {
    float4 xv0 = x4[k + 0], xv1 = x4[k + 1], xv2 = x4[k + 2], xv3 = x4[k + 3];
    float4 wv0 = w4[k + 0], wv1 = w4[k + 1], wv2 = w4[k + 2], wv3 = w4[k + 3];
    a0 = fmaf(wv0.w, xv0.w, fmaf(wv0.z, xv0.z, fmaf(wv0.y, xv0.y, fmaf(wv0.x, xv0.x, a0))));
    a1 = fmaf(wv1.w, xv1.w, fmaf(wv1.z, xv1.z, fmaf(wv1.y, xv1.y, fmaf(wv1.x, xv1.x, a1))));
    a2 = fmaf(wv2.w, xv2.w, fmaf(wv2.z, xv2.z, fmaf(wv2.y, xv2.y, fmaf(wv2.x, xv2.x, a2))));
    a3 = fmaf(wv3.w, xv3.w, fmaf(wv3.z, xv3.z, fmaf(wv3.y, xv3.y, fmaf(wv3.x, xv3.x, a3))));
  }
  return (a0 + a1) + (a2 + a3);
}

__global__ __launch_bounds__(256) void prep(P1 p) {
  __shared__ __align__(16) float s_src[2][16];
  __shared__ __align__(16) float s_x2[2][128];
  __shared__ __align__(16) float s_y[2][128];
  __shared__ float s_red[2][2];

  const int tid = threadIdx.x;
  const int rl  = tid >> 7;
  const int d   = tid & 127;
  const int row = blockIdx.x * 2 + rl;
  volatile float* red = s_red[rl];

  if (d < 14) s_src[rl][d + 1] = p.src[row * 14 + d];
  if (d == 14) { s_src[rl][0] = 0.f; s_src[rl][15] = 0.f; }
  __syncthreads();

  const float fw0 = p.fc_w[3*d+0], fw1 = p.fc_w[3*d+1], fw2 = p.fc_w[3*d+2];
  const float gw0 = p.gc_w[3*d+0], gw1 = p.gc_w[3*d+1], gw2 = p.gc_w[3*d+2];
  const float fb = p.fc_b[d], gb = p.gc_b[d];
  float g = 0.f;
#pragma unroll
  for (int m = 0; m < 14; ++m) {
    float xm1 = s_src[rl][m], x0v = s_src[rl][m+1], xp1 = s_src[rl][m+2];
    float f  = fmaf(fw2, xp1, fmaf(fw1, x0v, fmaf(fw0, xm1, fb)));
    float ga = fmaf(gw2, xp1, fmaf(gw1, x0v, fmaf(gw0, xm1, gb)));
    g = fmaf(f, 1.f / (1.f + expf(-ga)), g);
  }
  g *= (1.f / 14.f);

  float mu = rowReduceSum(g, red, d) * (1.f / 128.f);
  float cg = g - mu;
  float var = rowReduceSum(cg * cg, red, d) * (1.f / 128.f);
  float x = fmaf(p.ln_w[d], cg * rsqrtf(var + 1e-5f), p.ln_b[d]);

  const int tval = *p.t;
  {
    int i2 = d >> 1;
    float arg = (float)tval * expf((float)i2 * -PE_C);
    float pe = (d & 1) ? cosf(arg) : sinf(arg);
    x = fmaf(x, SQRT_D, pe);
  }
  p.x0[row * 128 + d] = x;

  float mu1 = rowReduceSum(x, red, d) * (1.f / 128.f);
  float c1 = x - mu1;
  float v1 = rowReduceSum(c1 * c1, red, d) * (1.f / 127.f);
  s_x2[rl][d] = fmaf(p.n1a[d], c1 / (sqrtf(v1) + 1e-6f), p.n1b[d]);
  __syncthreads();

  float y = p.vb[d] + dot128s(p.vw + d * 128, s_x2[rl]);
  s_y[rl][d] = y;
  __syncthreads();
  p.a0[row * 128 + d] = p.ob[d] + dot128s(p.ow + d * 128, s_y[rl]);
}

// ---------------- K2: per-batch megakernel ----------------
struct P2 {
  const float* x0; const float* a0;
  const f16x2 *qw16, *kw16, *vw16, *ow16, *w116, *w216;
  const float *qb, *kb, *vb, *ob;
  const float *n1a, *n1b, *n2a, *n2b;
  const float *b1, *b2;
  const float *fna, *fnb, *out_w, *out_b;
  float* out;
};

// norm (_norm: ddof=1, eps on std) of sX row j -> packed f16x2[64]
__device__ __forceinline__ void norm_row_to_h2(const float* sX, int j,
    const float* __restrict__ na, const float* __restrict__ nb, f16x2* out) {
  float mu = 0.f;
#pragma unroll 16
  for (int d = 0; d < 128; ++d) mu += sX[XS(j, d)];
  mu *= (1.f / 128.f);
  float var = 0.f;
#pragma unroll 16
  for (int d = 0; d < 128; ++d) { float c = sX[XS(j, d)] - mu; var = fmaf(c, c, var); }
  const float inv = 1.f / (sqrtf(var * (1.f / 127.f)) + 1e-6f);
#pragma unroll
  for (int d2 = 0; d2 < 64; ++d2) {
    float a = fmaf(na[2*d2]   * inv, sX[XS(j, 2*d2)]   - mu, nb[2*d2]);
    float b = fmaf(na[2*d2+1] * inv, sX[XS(j, 2*d2+1)] - mu, nb[2*d2+1]);
    out[d2] = mk2(a, b);
  }
}

// norm2 + FFN (relu(x2@w1^T+b1)@w2^T+b2), residual flushed into sX chunk-wise
__device__ __forceinline__ void ffn_phase(float* sX, f16x2* sAux, int t,
    const float* __restrict__ na, const float* __restrict__ nb,
    const f16x2* __restrict__ w1, const float* __restrict__ b1,
    const f16x2* __restrict__ w2, const float* __restrict__ b2) {
  const int j = t & 255, half = t >> 8;
  const int dh = half * 64;
  f16x2 x2h[64];
  norm_row_to_h2(sX, j, na, nb, x2h);
  for (int c = 0; c < 8; ++c) {            // u-chunks of 64
    for (int u0 = 0; u0 < 32; u0 += 2) {
      const int u = c * 64 + half * 32 + u0;
      float h0 = b1[u], h1 = b1[u + 1];
      const f16x2* __restrict__ r0 = w1 + u * 64;
      const f16x2* __restrict__ r1 = r0 + 64;
#pragma unroll
      for (int k = 0; k < 64; ++k) { h0 = FDOT2(x2h[k], r0[k], h0); h1 = FDOT2(x2h[k], r1[k], h1); }
      const int u2 = half * 16 + (u0 >> 1);
      sAux[j * 32 + (u2 ^ (j & 31))] = mk2(fmaxf(h0, 0.f), fmaxf(h1, 0.f));
    }
    __syncthreads();
    f16x2 hrow[32];
#pragma unroll
    for (int u2 = 0; u2 < 32; ++u2) hrow[u2] = sAux[j * 32 + (u2 ^ (j & 31))];
    for (int dg = 0; dg < 8; ++dg) {
      float aa[8];
#pragma unroll
      for (int dd = 0; dd < 8; ++dd) {
        const int d = dh + dg * 8 + dd;
        float a = (c == 0) ? b2[d] : 0.f;
        const f16x2* __restrict__ w2r = w2 + d * 256 + c * 32;
#pragma unroll
        for (int u2 = 0; u2 < 32; ++u2) a = FDOT2(hrow[u2], w2r[u2], a);
        aa[dd] = a;
      }
#pragma unroll
      for (int dd = 0; dd < 8; ++dd) sX[XS(j, dh + dg * 8 + dd)] += aa[dd];
    }
    __syncthreads();
  }
}

__device__ __forceinline__ void attn_phase(float* sX, f16x2* sAux, int t, const P2& p) {
  const int jg = t & 255, ghalf = t >> 8;   // gen mapping: row jg, K- or V-half
  const int jq = t >> 1,  kh = t & 1;       // flash mapping: row jq, k'-parity
  const float* __restrict__ n1a = p.n1a + 128;
  const float* __restrict__ n1b = p.n1b + 128;
  const float* __restrict__ qb = p.qb + 128;
  const float* __restrict__ kb = p.kb + 128;
  const float* __restrict__ vb = p.vb + 128;
  const float* __restrict__ ob = p.ob + 128;
  const f16x2* __restrict__ qw = p.qw16 + 8192;  // layer-1 slice
  const f16x2* __restrict__ kw = p.kw16 + 8192;
  const f16x2* __restrict__ vw = p.vw16 + 8192;
  const f16x2* __restrict__ ow = p.ow16 + 8192;

  // ---- hoist: q fragments for ALL 4 heads while x2q is live, then x2q dies
  f16x2 q2all[4][16];
  {
    f16x2 x2q[64];
    norm_row_to_h2(sX, jq, n1a, n1b, x2q);
#pragma unroll
    for (int h = 0; h < 4; ++h) {
      for (int c2 = 0; c2 < 16; ++c2) {
        const int c = h * 32 + 2 * c2;
        float o0 = qb[c], o1 = qb[c + 1];
        const f16x2* __restrict__ r0 = qw + c * 64;
        const f16x2* __restrict__ r1 = r0 + 64;
#pragma unroll
        for (int k = 0; k < 64; ++k) { o0 = FDOT2(x2q[k], r0[k], o0); o1 = FDOT2(x2q[k], r1[k], o1); }
        q2all[h][c2] = mk2(o0 * INV_SQRT_DK, o1 * INV_SQRT_DK);
      }
    }
  }

  // only ONE normalized row stays live across the head loop
  f16x2 x2g[64];
  norm_row_to_h2(sX, jg, n1a, n1b, x2g);

  const f16x2* __restrict__ wg = ghalf ? vw : kw;
  const float* __restrict__ bg = ghalf ? vb : kb;
  const int lbase = ghalf ? 4096 : 0;       // sK @ 0, sV @ 4096 (f16x2 units)

#pragma unroll
  for (int h = 0; h < 4; ++h) {
    const int hb = h * 32;
    // ---- gen K (ghalf=0) / V (ghalf=1) for row jg ----
    for (int c2 = 0; c2 < 16; ++c2) {
      const int c = hb + 2 * c2;
      float o0 = bg[c], o1 = bg[c + 1];
      const f16x2* __restrict__ r0 = wg + c * 64;
      const f16x2* __restrict__ r1 = r0 + 64;
#pragma unroll
      for (int k = 0; k < 64; ++k) { o0 = FDOT2(x2g[k], r0[k], o0); o1 = FDOT2(x2g[k], r1[k], o1); }
      sAux[lbase + jg * 16 + (c2 ^ (jg & 15))] = mk2(o0, o1);
    }
    __syncthreads();

    // ---- online-softmax flash over k' = kh, kh+2, ... ----
    float m_run = -1e30f, lsum = 0.f;
    float o[32];
#pragma unroll
    for (int c = 0; c < 32; ++c) o[c] = 0.f;
    for (int k2 = 0; k2 < 128; ++k2) {
      const int kk = 2 * k2 + kh;
      const f16x2* __restrict__ krow = sAux + kk * 16;
      float s = 0.f;
#pragma unroll
      for (int c2 = 0; c2 < 16; ++c2) s = FDOT2(q2all[h][c2], krow[c2 ^ (kk & 15)], s);
      float pc;
      if (s > m_run) {
        const float corr = __expf(m_run - s);
        lsum *= corr;
#pragma unroll
        for (int c = 0; c < 32; ++c) o[c] *= corr;
        m_run = s; pc = 1.f;
      } else {
        pc = __expf(s - m_run);
      }
      lsum += pc;
      const f16x2* __restrict__ vrow = sAux + 4096 + kk * 16;
#pragma unroll
      for (int c2 = 0; c2 < 16; ++c2) {
        const f16x2 vv = vrow[c2 ^ (kk & 15)];
        o[2*c2]   = fmaf(pc, (float)vv.x, o[2*c2]);
        o[2*c2+1] = fmaf(pc, (float)vv.y, o[2*c2+1]);
      }
    }
    // ---- merge lane pair (even/odd k') ----
    const float mo = __shfl_xor(m_run, 1);
    const float lo = __shfl_xor(lsum, 1);
    const float m2 = fmaxf(m_run, mo);
    const float ea = __expf(m_run - m2), eb = __expf(mo - m2);
    const float linv = 1.f / fmaf(lsum, ea, lo * eb);
    f16x2 oh[16];
#pragma unroll
    for (int c2 = 0; c2 < 16; ++c2) {
      const float p0 = fmaf(o[2*c2],   ea, __shfl_xor(o[2*c2],   1) * eb) * linv;
      const float p1 = fmaf(o[2*c2+1], ea, __shfl_xor(o[2*c2+1], 1) * eb) * linv;
      oh[c2] = mk2(p0, p1);
    }
    // ---- O-projection partial residual into sX (own d-half) ----
    const int db = kh * 64;
    for (int dg = 0; dg < 8; ++dg) {
      float aa[8];
#pragma unroll
      for (int dd = 0; dd < 8; ++dd) {
        const int d = db + dg * 8 + dd;
        const f16x2* __restrict__ owr = ow + d * 64 + (hb >> 1);
        float a = (h == 0) ? ob[d] : 0.f;
#pragma unroll
        for (int c2 = 0; c2 < 16; ++c2) a = FDOT2(oh[c2], owr[c2], a);
        aa[dd] = a;
      }
#pragma unroll
      for (int dd = 0; dd < 8; ++dd) sX[XS(jq, db + dg * 8 + dd)] += aa[dd];
    }
    __syncthreads();
  }
}

__global__ __launch_bounds__(512, 1) void batchk(P2 p) {
  __shared__ float sX[32768];      // 128 KB residual stream, XS-swizzled
  __shared__ f16x2 sAux[8192];     // 32 KB: FFN H-chunk | attn K,V
  const int t = threadIdx.x;
  const int i = blockIdx.x;

  // Phase A: X[i,j,:] = x0[j] + a0[i]
  for (int k = 0; k < 64; ++k) {
    const int idx = t + 512 * k;
    const int j = idx >> 7, d = idx & 127;
    sX[XS(j, d)] = p.x0[idx] + p.a0[i * 128 + d];
  }
  __syncthreads();

  ffn_phase(sX, sAux, t, p.n2a, p.n2b, p.w116, p.b1, p.w216, p.b2);
  attn_phase(sX, sAux, t, p);
  ffn_phase(sX, sAux, t, p.n2a + 128, p.n2b + 128,
            p.w116 + 32768, p.b1 + 512, p.w216 + 32768, p.b2 + 128);

  // Phase D: final norm + output projection
  {
    const int j = t >> 1, hd = t & 1;
    float mu = 0.f, var = 0.f;
#pragma unroll 16
    for (int d = 0; d < 128; ++d) mu += sX[XS(j, d)];
    mu *= (1.f / 128.f);
#pragma unroll 16
    for (int d = 0; d < 128; ++d) { float c = sX[XS(j, d)] - mu; var = fmaf(c, c, var); }
    const float inv = 1.f / (sqrtf(var * (1.f / 127.f)) + 1e-6f);
    float os = 0.f;
    for (int d0 = 0; d0 < 64; ++d0) {
      const int d = hd * 64 + d0;
      const float xv = fmaf(p.fna[d] * inv, sX[XS(j, d)] - mu, p.fnb[d]);
      os = fmaf(xv, p.out_w[d], os);
    }
    os += __shfl_xor(os, 1);
    if (hd == 0) p.out[i * 256 + j] = os + p.out_b[0];
  }
}

// ---------------- host ----------------
extern "C" void kernel_launch(void* const* d_in, const int* in_sizes, int n_in,
                              void* d_out, int out_size, void* d_ws, size_t ws_size,
                              hipStream_t stream) {
  float* x0 = (float*)d_ws;                       // 32768 f32
  float* a0 = x0 + 32768;                         // 32768 f32
  _Float16* W16 = (_Float16*)((char*)d_ws + 262144);  // 393216 halves

  P0 p0;
  p0.qw = (const float*)d_in[8];  p0.kw = (const float*)d_in[10];
  p0.vw = (const float*)d_in[12]; p0.ow = (const float*)d_in[14];
  p0.w1 = (const float*)d_in[20]; p0.w2 = (const float*)d_in[22];
  p0.dst = W16;
  convf16<<<dim3(1536), dim3(256), 0, stream>>>(p0);

  P1 p1;
  p1.src  = (const float*)d_in[0];
  p1.t    = (const int*)  d_in[1];
  p1.fc_w = (const float*)d_in[2];  p1.fc_b = (const float*)d_in[3];
  p1.gc_w = (const float*)d_in[4];  p1.gc_b = (const float*)d_in[5];
  p1.ln_w = (const float*)d_in[6];  p1.ln_b = (const float*)d_in[7];
  p1.n1a  = (const float*)d_in[16]; p1.n1b  = (const float*)d_in[17];
  p1.vw   = (const float*)d_in[12]; p1.vb   = (const float*)d_in[13];
  p1.ow   = (const float*)d_in[14]; p1.ob   = (const float*)d_in[15];
  p1.x0 = x0; p1.a0 = a0;
  prep<<<dim3(128), dim3(256), 0, stream>>>(p1);

  P2 p2;
  p2.x0 = x0; p2.a0 = a0;
  p2.qw16 = (const f16x2*)W16;
  p2.kw16 = p2.qw16 + 16384;
  p2.vw16 = p2.kw16 + 16384;
  p2.ow16 = p2.vw16 + 16384;
  p2.w116 = p2.ow16 + 16384;     // 65536 f16x2
  p2.w216 = p2.w116 + 65536;
  p2.qb = (const float*)d_in[9];  p2.kb = (const float*)d_in[11];
  p2.vb = (const float*)d_in[13]; p2.ob = (const float*)d_in[15];
  p2.n1a = (const float*)d_in[16]; p2.n1b = (const float*)d_in[17];
  p2.n2a = (const float*)d_in[18]; p2.n2b = (const float*)d_in[19];
  p2.b1 = (const float*)d_in[21];  p2.b2 = (const float*)d_in[23];
  p2.fna = (const float*)d_in[24]; p2.fnb = (const float*)d_in[25];
  p2.out_w = (const float*)d_in[26]; p2.out_b = (const float*)d_in[27];
  p2.out = (float*)d_out;
  batchk<<<dim3(256), dim3(512), 0, stream>>>(p2);
}

// Round 6
// 259.682 us; speedup vs baseline: 24.1132x; 8.2794x over previous
//
#include <hip/hip_runtime.h>
#include <math.h>

// r6: full-MFMA megakernel (16x16x32 f16, fp32 accum).
// Structure (verified r3-r5): X[i,j,:] = x0[j]+a0[i]; per block i:
//   FFN0 -> layer-1 4-head seq-256 attention -> FFN1 -> final norm -> out.
// All GEMMs transposed: A = row-major weights (16B frags from global/L1),
// B = activations^T built from prior C/D accs via uniform-reg ds_bpermute.
// C/D layout (m89): col=lane&15, row=(lane>>4)*4+reg.
// A: lane l -> A[l&15][8*(l>>4)+j]; B: lane l -> B[8*(l>>4)+j][l&15].

#define SQRT_D 11.313708498984761f
#define PE_C   0.14391156831212787f
#define INV_SQRT_DK 0.17677669529663687f

typedef _Float16 f16x8 __attribute__((ext_vector_type(8)));
typedef float    f32x4 __attribute__((ext_vector_type(4)));

#define MFMA(a, b, c) __builtin_amdgcn_mfma_f32_16x16x32_f16((a), (b), (c), 0, 0, 0)

__device__ __forceinline__ float bpermf(int addr, float v) {
  return __int_as_float(__builtin_amdgcn_ds_bpermute(addr, __float_as_int(v)));
}

// B-frag from two C/D accumulator tiles (k-dim = 2 M-tiles of source).
// elem j of lane l = src tile (hiSel? cB : cA), reg j&3,
// src lane = (((l>>4)&1)*2 + (j>>2))*16 + (l&15).
__device__ __forceinline__ f16x8 make_bfrag(f32x4 cA, f32x4 cB, int aLo, int aHi, int hiSel) {
  f16x8 r;
#pragma unroll
  for (int j = 0; j < 8; ++j) {
    const int ad = (j < 4) ? aLo : aHi;
    float va = bpermf(ad, cA[j & 3]);
    float vb = bpermf(ad, cB[j & 3]);
    r[j] = (_Float16)(hiSel ? vb : va);
  }
  return r;
}

// ---------------- K0: weight f32 -> f16 ----------------
struct P0 { const float *qw, *kw, *vw, *ow, *w1, *w2; _Float16* dst; };

__global__ __launch_bounds__(256) void convf16(P0 p) {
  const int idx = blockIdx.x * 256 + threadIdx.x;
  float v;
  if      (idx <  32768) v = p.qw[idx];
  else if (idx <  65536) v = p.kw[idx -  32768];
  else if (idx <  98304) v = p.vw[idx -  65536];
  else if (idx < 131072) v = p.ow[idx -  98304];
  else if (idx < 262144) v = p.w1[idx - 131072];
  else                   v = p.w2[idx - 262144];
  p.dst[idx] = (_Float16)v;
}

// ---------------- K1: prep (verified r3) ----------------
struct P1 {
  const float* src; const int* t;
  const float* fc_w; const float* fc_b; const float* gc_w; const float* gc_b;
  const float* ln_w; const float* ln_b;
  const float* n1a; const float* n1b;
  const float* vw; const float* vb; const float* ow; const float* ob;
  float* x0; float* a0;
};

__device__ __forceinline__ float rowReduceSum(float v, volatile float* red, int d) {
#pragma unroll
  for (int off = 32; off > 0; off >>= 1) v += __shfl_xor(v, off, 64);
  if ((d & 63) == 0) red[d >> 6] = v;
  __syncthreads();
  float r = red[0] + red[1];
  __syncthreads();
  return r;
}

__device__ __forceinline__ float dot128s(const float* __restrict__ w,
                                         const float* __restrict__ xs) {
  const float4* __restrict__ w4 = (const float4*)w;
  const float4* __restrict__ x4 = (const float4*)xs;
  float a0 = 0.f, a1 = 0.f, a2 = 0.f, a3 = 0.f;
#pragma unroll
  for (int k = 0; k < 32; k += 4) {
    float4 xv0 = x4[k + 0], xv1 = x4[k + 1], xv2 = x4[k + 2], xv3 = x4[k + 3];
    float4 wv0 = w4[k + 0], wv1 = w4[k + 1], wv2 = w4[k + 2], wv3 = w4[k + 3];
    a0 = fmaf(wv0.w, xv0.w, fmaf(wv0.z, xv0.z, fmaf(wv0.y, xv0.y, fmaf(wv0.x, xv0.x, a0))));
    a1 = fmaf(wv1.w, xv1.w, fmaf(wv1.z, xv1.z, fmaf(wv1.y, xv1.y, fmaf(wv1.x, xv1.x, a1))));
    a2 = fmaf(wv2.w, xv2.w, fmaf(wv2.z, xv2.z, fmaf(wv2.y, xv2.y, fmaf(wv2.x, xv2.x, a2))));
    a3 = fmaf(wv3.w, xv3.w, fmaf(wv3.z, xv3.z, fmaf(wv3.y, xv3.y, fmaf(wv3.x, xv3.x, a3))));
  }
  return (a0 + a1) + (a2 + a3);
}

__global__ __launch_bounds__(256) void prep(P1 p) {
  __shared__ __align__(16) float s_src[2][16];
  __shared__ __align__(16) float s_x2[2][128];
  __shared__ __align__(16) float s_y[2][128];
  __shared__ float s_red[2][2];

  const int tid = threadIdx.x;
  const int rl  = tid >> 7;
  const int d   = tid & 127;
  const int row = blockIdx.x * 2 + rl;
  volatile float* red = s_red[rl];

  if (d < 14) s_src[rl][d + 1] = p.src[row * 14 + d];
  if (d == 14) { s_src[rl][0] = 0.f; s_src[rl][15] = 0.f; }
  __syncthreads();

  const float fw0 = p.fc_w[3*d+0], fw1 = p.fc_w[3*d+1], fw2 = p.fc_w[3*d+2];
  const float gw0 = p.gc_w[3*d+0], gw1 = p.gc_w[3*d+1], gw2 = p.gc_w[3*d+2];
  const float fb = p.fc_b[d], gb = p.gc_b[d];
  float g = 0.f;
#pragma unroll
  for (int m = 0; m < 14; ++m) {
    float xm1 = s_src[rl][m], x0v = s_src[rl][m+1], xp1 = s_src[rl][m+2];
    float f  = fmaf(fw2, xp1, fmaf(fw1, x0v, fmaf(fw0, xm1, fb)));
    float ga = fmaf(gw2, xp1, fmaf(gw1, x0v, fmaf(gw0, xm1, gb)));
    g = fmaf(f, 1.f / (1.f + expf(-ga)), g);
  }
  g *= (1.f / 14.f);

  float mu = rowReduceSum(g, red, d) * (1.f / 128.f);
  float cg = g - mu;
  float var = rowReduceSum(cg * cg, red, d) * (1.f / 128.f);
  float x = fmaf(p.ln_w[d], cg * rsqrtf(var + 1e-5f), p.ln_b[d]);

  const int tval = *p.t;
  {
    int i2 = d >> 1;
    float arg = (float)tval * expf((float)i2 * -PE_C);
    float pe = (d & 1) ? cosf(arg) : sinf(arg);
    x = fmaf(x, SQRT_D, pe);
  }
  p.x0[row * 128 + d] = x;

  float mu1 = rowReduceSum(x, red, d) * (1.f / 128.f);
  float c1 = x - mu1;
  float v1 = rowReduceSum(c1 * c1, red, d) * (1.f / 127.f);
  s_x2[rl][d] = fmaf(p.n1a[d], c1 / (sqrtf(v1) + 1e-6f), p.n1b[d]);
  __syncthreads();

  float y = p.vb[d] + dot128s(p.vw + d * 128, s_x2[rl]);
  s_y[rl][d] = y;
  __syncthreads();
  p.a0[row * 128 + d] = p.ob[d] + dot128s(p.ow + d * 128, s_y[rl]);
}

// ---------------- K2: per-batch MFMA megakernel ----------------
struct P2 {
  const float* x0; const float* a0;
  const _Float16 *wq, *wk, *wvv, *wo, *w1h, *w2h;
  const float *qb, *kb, *vb, *ob;
  const float *n1a, *n1b, *n2a, *n2b;
  const float *b1, *b2;
  const float *fna, *fnb, *out_w, *out_b;
  float* out;
};

// row stats (ddof=1, eps on std) for the wave's 32-row strip, distributed to
// the frag mapping (mu/inv for row nt*16+(l&15)) via bpermute. No LDS/barrier.
__device__ __forceinline__ void row_stats(const float* sX, int strip, int l,
    float& mu0, float& inv0, float& mu1, float& inv1) {
  const int rl = l & 31, hf = l >> 5;
  const float* base = sX + (strip + rl) * 132 + hf * 64;
  float sum = 0.f, sq = 0.f;
#pragma unroll
  for (int c = 0; c < 16; ++c) {
    f32x4 v = *(const f32x4*)(base + c * 4);
#pragma unroll
    for (int e = 0; e < 4; ++e) { sum += v[e]; sq = fmaf(v[e], v[e], sq); }
  }
  sum += __shfl_xor(sum, 32);
  sq  += __shfl_xor(sq, 32);
  float mu = sum * (1.f / 128.f);
  float var = fmaf(-sum, mu, sq) * (1.f / 127.f);
  float inv = 1.f / (sqrtf(var) + 1e-6f);
  const int l15 = l & 15;
  mu0 = bpermf(l15 * 4, mu);         inv0 = bpermf(l15 * 4, inv);
  mu1 = bpermf((16 + l15) * 4, mu);  inv1 = bpermf((16 + l15) * 4, inv);
}

// X2n^T B-frags [kt][nt] for the wave's strip.
__device__ __forceinline__ void build_x2(const float* sX, int strip, int l,
    const float* __restrict__ na, const float* __restrict__ nb, f16x8 x2f[4][2]) {
  float mu0, inv0, mu1, inv1;
  row_stats(sX, strip, l, mu0, inv0, mu1, inv1);
  const int l15 = l & 15, lg = l >> 4;
#pragma unroll
  for (int kt = 0; kt < 4; ++kt) {
    const int d0 = kt * 32 + lg * 8;
    f32x4 naA = *(const f32x4*)(na + d0), naB = *(const f32x4*)(na + d0 + 4);
    f32x4 nbA = *(const f32x4*)(nb + d0), nbB = *(const f32x4*)(nb + d0 + 4);
#pragma unroll
    for (int nt = 0; nt < 2; ++nt) {
      const float mu = nt ? mu1 : mu0, inv = nt ? inv1 : inv0;
      const float* xr = sX + (strip + nt * 16 + l15) * 132 + d0;
      f32x4 xA = *(const f32x4*)(xr), xB = *(const f32x4*)(xr + 4);
      f16x8 f;
#pragma unroll
      for (int e = 0; e < 4; ++e) {
        f[e]     = (_Float16)fmaf(naA[e] * inv, xA[e] - mu, nbA[e]);
        f[e + 4] = (_Float16)fmaf(naB[e] * inv, xB[e] - mu, nbB[e]);
      }
      x2f[kt][nt] = f;
    }
  }
}

// norm2 + FFN, residual flushed into sX per 128-u chunk.
__device__ __forceinline__ void ffn_phase(float* sX, int strip, int l,
    const float* __restrict__ na, const float* __restrict__ nb,
    const _Float16* __restrict__ w1, const float* __restrict__ b1,
    const _Float16* __restrict__ w2, const float* __restrict__ b2,
    int aLo, int aHi, int hiSel) {
  f16x8 x2f[4][2];
  build_x2(sX, strip, l, na, nb, x2f);
  const int l15 = l & 15, lg = l >> 4;
#pragma unroll
  for (int c = 0; c < 4; ++c) {
    f32x4 hacc[8][2];
#pragma unroll
    for (int mt = 0; mt < 8; ++mt) {
      f32x4 bias = *(const f32x4*)(b1 + c * 128 + mt * 16 + lg * 4);
      hacc[mt][0] = bias; hacc[mt][1] = bias;
    }
#pragma unroll
    for (int mt = 0; mt < 8; ++mt)
#pragma unroll
      for (int kt = 0; kt < 4; ++kt) {
        f16x8 a = *(const f16x8*)(w1 + (c * 128 + mt * 16 + l15) * 128 + kt * 32 + lg * 8);
        hacc[mt][0] = MFMA(a, x2f[kt][0], hacc[mt][0]);
        hacc[mt][1] = MFMA(a, x2f[kt][1], hacc[mt][1]);
      }
#pragma unroll
    for (int mt = 0; mt < 8; ++mt)
#pragma unroll
      for (int nt = 0; nt < 2; ++nt)
#pragma unroll
        for (int e = 0; e < 4; ++e) hacc[mt][nt][e] = fmaxf(hacc[mt][nt][e], 0.f);
    f16x8 hf[4][2];
#pragma unroll
    for (int kt = 0; kt < 4; ++kt) {
      hf[kt][0] = make_bfrag(hacc[kt * 2][0], hacc[kt * 2 + 1][0], aLo, aHi, hiSel);
      hf[kt][1] = make_bfrag(hacc[kt * 2][1], hacc[kt * 2 + 1][1], aLo, aHi, hiSel);
    }
    f32x4 oacc[8][2];
#pragma unroll
    for (int mt = 0; mt < 8; ++mt) {
      if (c == 0) {
        f32x4 bias = *(const f32x4*)(b2 + mt * 16 + lg * 4);
        oacc[mt][0] = bias; oacc[mt][1] = bias;
      } else {
        f32x4 z = {0.f, 0.f, 0.f, 0.f};
        oacc[mt][0] = z; oacc[mt][1] = z;
      }
    }
#pragma unroll
    for (int mt = 0; mt < 8; ++mt)
#pragma unroll
      for (int kt = 0; kt < 4; ++kt) {
        f16x8 a = *(const f16x8*)(w2 + (mt * 16 + l15) * 512 + c * 128 + kt * 32 + lg * 8);
        oacc[mt][0] = MFMA(a, hf[kt][0], oacc[mt][0]);
        oacc[mt][1] = MFMA(a, hf[kt][1], oacc[mt][1]);
      }
#pragma unroll
    for (int mt = 0; mt < 8; ++mt)
#pragma unroll
      for (int nt = 0; nt < 2; ++nt) {
        float* dst = sX + (strip + nt * 16 + l15) * 132 + mt * 16 + lg * 4;
        f32x4 v = *(const f32x4*)dst;
#pragma unroll
        for (int e = 0; e < 4; ++e) v[e] += oacc[mt][nt][e];
        *(f32x4*)dst = v;
      }
  }
}

__global__ void __launch_bounds__(512) __attribute__((amdgpu_waves_per_eu(2, 2)))
batchk(P2 p) {
  __shared__ __align__(16) float sX[256 * 132];     // 135168 B
  __shared__ __align__(16) _Float16 sKV[8192];      // 16 KB, K then VT per head

  const int t = threadIdx.x;
  const int i = blockIdx.x;
  const int l = t & 63;
  const int wv = t >> 6;
  const int strip = wv * 32;
  const int l15 = l & 15;
  const int lg = l >> 4;
  const int hiSel = (l >> 5) & 1;
  const int aLo = ((((lg & 1) * 2 + 0) * 16) + l15) * 4;
  const int aHi = ((((lg & 1) * 2 + 1) * 16) + l15) * 4;

  // ---- Phase A: X[i,j,:] = x0[j] + a0[i] (each wave fills its own strip) ----
  {
    const int j = t >> 1, hf = t & 1;
    const float* xr = p.x0 + j * 128 + hf * 64;
    const float* ar = p.a0 + i * 128 + hf * 64;
    float* dst = sX + j * 132 + hf * 64;
#pragma unroll
    for (int c = 0; c < 16; ++c) {
      f32x4 a = *(const f32x4*)(xr + c * 4);
      f32x4 b = *(const f32x4*)(ar + c * 4);
#pragma unroll
      for (int e = 0; e < 4; ++e) a[e] += b[e];
      *(f32x4*)(dst + c * 4) = a;
    }
  }

  // ---- FFN0 (layer-0 n2/w1/w2), own strip only: no barrier needed ----
  ffn_phase(sX, strip, l, p.n2a, p.n2b, p.w1h, p.b1, p.w2h, p.b2, aLo, aHi, hiSel);

  // ---- layer-1 attention ----
  {
    const float* n1a = p.n1a + 128;
    const float* n1b = p.n1b + 128;
    f16x8 x2f[4][2];
    build_x2(sX, strip, l, n1a, n1b, x2f);

#pragma unroll
    for (int h = 0; h < 4; ++h) {
      // K gen (dk 32 = 2 Mtiles) for own strip
      f32x4 kacc[2][2];
#pragma unroll
      for (int mt = 0; mt < 2; ++mt) {
        f32x4 b4 = *(const f32x4*)(p.kb + 128 + h * 32 + mt * 16 + lg * 4);
        kacc[mt][0] = b4; kacc[mt][1] = b4;
      }
#pragma unroll
      for (int mt = 0; mt < 2; ++mt)
#pragma unroll
        for (int kt = 0; kt < 4; ++kt) {
          f16x8 a = *(const f16x8*)(p.wk + 16384 + (h * 32 + mt * 16 + l15) * 128 + kt * 32 + lg * 8);
          kacc[mt][0] = MFMA(a, x2f[kt][0], kacc[mt][0]);
          kacc[mt][1] = MFMA(a, x2f[kt][1], kacc[mt][1]);
        }
      // write K rows to LDS: sK[j][d ^ ((j&3)<<3)]
#pragma unroll
      for (int mt = 0; mt < 2; ++mt)
#pragma unroll
        for (int nt = 0; nt < 2; ++nt)
#pragma unroll
          for (int e = 0; e < 4; ++e) {
            const int d = mt * 16 + lg * 4 + e;
            const int j = strip + nt * 16 + l15;
            sKV[j * 32 + (d ^ ((j & 3) << 3))] = (_Float16)kacc[mt][nt][e];
          }
      // Q gen (scale folded in, incl bias)
      f32x4 qacc[2][2];
#pragma unroll
      for (int mt = 0; mt < 2; ++mt) {
        f32x4 b4 = *(const f32x4*)(p.qb + 128 + h * 32 + mt * 16 + lg * 4);
        qacc[mt][0] = b4; qacc[mt][1] = b4;
      }
#pragma unroll
      for (int mt = 0; mt < 2; ++mt)
#pragma unroll
        for (int kt = 0; kt < 4; ++kt) {
          f16x8 a = *(const f16x8*)(p.wq + 16384 + (h * 32 + mt * 16 + l15) * 128 + kt * 32 + lg * 8);
          qacc[mt][0] = MFMA(a, x2f[kt][0], qacc[mt][0]);
          qacc[mt][1] = MFMA(a, x2f[kt][1], qacc[mt][1]);
        }
#pragma unroll
      for (int mt = 0; mt < 2; ++mt)
#pragma unroll
        for (int nt = 0; nt < 2; ++nt)
#pragma unroll
          for (int e = 0; e < 4; ++e) qacc[mt][nt][e] *= INV_SQRT_DK;
      f16x8 qf[2];
      qf[0] = make_bfrag(qacc[0][0], qacc[1][0], aLo, aHi, hiSel);
      qf[1] = make_bfrag(qacc[0][1], qacc[1][1], aLo, aHi, hiSel);
      __syncthreads();  // K visible to all waves

      // S^T = K @ Q^T  (256 x 32 strip)
      f32x4 sacc[16][2];
#pragma unroll
      for (int mt = 0; mt < 16; ++mt) {
        const int k = mt * 16 + l15;
        f16x8 a = *(const f16x8*)(sKV + k * 32 + ((lg * 8) ^ ((k & 3) << 3)));
        f32x4 z = {0.f, 0.f, 0.f, 0.f};
        sacc[mt][0] = MFMA(a, qf[0], z);
        sacc[mt][1] = MFMA(a, qf[1], z);
      }
      // softmax over k (full 256): per-lane 64 vals + shfl over rowgroups
      float linv[2];
#pragma unroll
      for (int nt = 0; nt < 2; ++nt) {
        float m = -1e30f;
#pragma unroll
        for (int mt = 0; mt < 16; ++mt)
#pragma unroll
          for (int e = 0; e < 4; ++e) m = fmaxf(m, sacc[mt][nt][e]);
        m = fmaxf(m, __shfl_xor(m, 16));
        m = fmaxf(m, __shfl_xor(m, 32));
        float s = 0.f;
#pragma unroll
        for (int mt = 0; mt < 16; ++mt)
#pragma unroll
          for (int e = 0; e < 4; ++e) {
            float ev = __expf(sacc[mt][nt][e] - m);
            sacc[mt][nt][e] = ev;
            s += ev;
          }
        s += __shfl_xor(s, 16);
        s += __shfl_xor(s, 32);
        linv[nt] = 1.f / s;
      }
      // P^T B-frags (unnormalized; 1/sum folded into O)
      f16x8 pf[8][2];
#pragma unroll
      for (int kt = 0; kt < 8; ++kt) {
        pf[kt][0] = make_bfrag(sacc[kt * 2][0], sacc[kt * 2 + 1][0], aLo, aHi, hiSel);
        pf[kt][1] = make_bfrag(sacc[kt * 2][1], sacc[kt * 2 + 1][1], aLo, aHi, hiSel);
      }
      __syncthreads();  // all waves done reading K

      // V gen -> VT in the SAME LDS buffer: sVT[d][j ^ ((d&7)<<3)]
      f32x4 vacc[2][2];
#pragma unroll
      for (int mt = 0; mt < 2; ++mt) {
        f32x4 b4 = *(const f32x4*)(p.vb + 128 + h * 32 + mt * 16 + lg * 4);
        vacc[mt][0] = b4; vacc[mt][1] = b4;
      }
#pragma unroll
      for (int mt = 0; mt < 2; ++mt)
#pragma unroll
        for (int kt = 0; kt < 4; ++kt) {
          f16x8 a = *(const f16x8*)(p.wvv + 16384 + (h * 32 + mt * 16 + l15) * 128 + kt * 32 + lg * 8);
          vacc[mt][0] = MFMA(a, x2f[kt][0], vacc[mt][0]);
          vacc[mt][1] = MFMA(a, x2f[kt][1], vacc[mt][1]);
        }
#pragma unroll
      for (int mt = 0; mt < 2; ++mt)
#pragma unroll
        for (int nt = 0; nt < 2; ++nt)
#pragma unroll
          for (int e = 0; e < 4; ++e) {
            const int d = mt * 16 + lg * 4 + e;
            const int j = strip + nt * 16 + l15;
            sKV[d * 256 + (j ^ ((d & 7) << 3))] = (_Float16)vacc[mt][nt][e];
          }
      __syncthreads();  // VT visible

      // O^T = VT @ P^T, then scale cols by 1/sum
      f32x4 oacc[2][2];
      {
        f32x4 z = {0.f, 0.f, 0.f, 0.f};
        oacc[0][0] = z; oacc[0][1] = z; oacc[1][0] = z; oacc[1][1] = z;
      }
#pragma unroll
      for (int kt = 0; kt < 8; ++kt)
#pragma unroll
        for (int mt = 0; mt < 2; ++mt) {
          const int d = mt * 16 + l15;
          f16x8 a = *(const f16x8*)(sKV + d * 256 + ((kt * 32 + lg * 8) ^ ((d & 7) << 3)));
          oacc[mt][0] = MFMA(a, pf[kt][0], oacc[mt][0]);
          oacc[mt][1] = MFMA(a, pf[kt][1], oacc[mt][1]);
        }
#pragma unroll
      for (int mt = 0; mt < 2; ++mt)
#pragma unroll
        for (int nt = 0; nt < 2; ++nt)
#pragma unroll
          for (int e = 0; e < 4; ++e) oacc[mt][nt][e] *= linv[nt];
      f16x8 of[2];
      of[0] = make_bfrag(oacc[0][0], oacc[1][0], aLo, aHi, hiSel);
      of[1] = make_bfrag(oacc[0][1], oacc[1][1], aLo, aHi, hiSel);

      // Z^T = ow_h @ O^T + residual into sX (ob added at h==0)
      f32x4 zacc[8][2];
#pragma unroll
      for (int mt = 0; mt < 8; ++mt) {
        if (h == 0) {
          f32x4 b4 = *(const f32x4*)(p.ob + 128 + mt * 16 + lg * 4);
          zacc[mt][0] = b4; zacc[mt][1] = b4;
        } else {
          f32x4 z = {0.f, 0.f, 0.f, 0.f};
          zacc[mt][0] = z; zacc[mt][1] = z;
        }
      }
#pragma unroll
      for (int mt = 0; mt < 8; ++mt) {
        f16x8 a = *(const f16x8*)(p.wo + 16384 + (mt * 16 + l15) * 128 + h * 32 + lg * 8);
        zacc[mt][0] = MFMA(a, of[0], zacc[mt][0]);
        zacc[mt][1] = MFMA(a, of[1], zacc[mt][1]);
      }
#pragma unroll
      for (int mt = 0; mt < 8; ++mt)
#pragma unroll
        for (int nt = 0; nt < 2; ++nt) {
          float* dst = sX + (strip + nt * 16 + l15) * 132 + mt * 16 + lg * 4;
          f32x4 v = *(const f32x4*)dst;
#pragma unroll
          for (int e = 0; e < 4; ++e) v[e] += zacc[mt][nt][e];
          *(f32x4*)dst = v;
        }
      __syncthreads();  // protect sKV before next head's K writes
    }
  }

  // ---- FFN1 ----
  ffn_phase(sX, strip, l, p.n2a + 128, p.n2b + 128,
            p.w1h + 65536, p.b1 + 512, p.w2h + 65536, p.b2 + 128, aLo, aHi, hiSel);

  // ---- final norm + output projection ----
  {
    const int r = strip + (l & 31), hf = l >> 5;
    const float* base = sX + r * 132 + hf * 64;
    float sum = 0.f, sq = 0.f;
#pragma unroll
    for (int c = 0; c < 16; ++c) {
      f32x4 v = *(const f32x4*)(base + c * 4);
#pragma unroll
      for (int e = 0; e < 4; ++e) { sum += v[e]; sq = fmaf(v[e], v[e], sq); }
    }
    sum += __shfl_xor(sum, 32);
    sq  += __shfl_xor(sq, 32);
    float mu = sum * (1.f / 128.f);
    float var = fmaf(-sum, mu, sq) * (1.f / 127.f);
    float inv = 1.f / (sqrtf(var) + 1e-6f);
    float os = 0.f;
#pragma unroll
    for (int c = 0; c < 16; ++c) {
      f32x4 x  = *(const f32x4*)(base + c * 4);
      f32x4 fa = *(const f32x4*)(p.fna + hf * 64 + c * 4);
      f32x4 fb = *(const f32x4*)(p.fnb + hf * 64 + c * 4);
      f32x4 wo = *(const f32x4*)(p.out_w + hf * 64 + c * 4);
#pragma unroll
      for (int e = 0; e < 4; ++e)
        os = fmaf(fmaf(fa[e] * inv, x[e] - mu, fb[e]), wo[e], os);
    }
    os += __shfl_xor(os, 32);
    if (l < 32) p.out[i * 256 + r] = os + p.out_b[0];
  }
}

// ---------------- host ----------------
extern "C" void kernel_launch(void* const* d_in, const int* in_sizes, int n_in,
                              void* d_out, int out_size, void* d_ws, size_t ws_size,
                              hipStream_t stream) {
  float* x0 = (float*)d_ws;                           // 32768 f32
  float* a0 = x0 + 32768;                             // 32768 f32
  _Float16* W16 = (_Float16*)((char*)d_ws + 262144);  // 393216 halves

  P0 p0;
  p0.qw = (const float*)d_in[8];  p0.kw = (const float*)d_in[10];
  p0.vw = (const float*)d_in[12]; p0.ow = (const float*)d_in[14];
  p0.w1 = (const float*)d_in[20]; p0.w2 = (const float*)d_in[22];
  p0.dst = W16;
  convf16<<<dim3(1536), dim3(256), 0, stream>>>(p0);

  P1 p1;
  p1.src  = (const float*)d_in[0];
  p1.t    = (const int*)  d_in[1];
  p1.fc_w = (const float*)d_in[2];  p1.fc_b = (const float*)d_in[3];
  p1.gc_w = (const float*)d_in[4];  p1.gc_b = (const float*)d_in[5];
  p1.ln_w = (const float*)d_in[6];  p1.ln_b = (const float*)d_in[7];
  p1.n1a  = (const float*)d_in[16]; p1.n1b  = (const float*)d_in[17];
  p1.vw   = (const float*)d_in[12]; p1.vb   = (const float*)d_in[13];
  p1.ow   = (const float*)d_in[14]; p1.ob   = (const float*)d_in[15];
  p1.x0 = x0; p1.a0 = a0;
  prep<<<dim3(128), dim3(256), 0, stream>>>(p1);

  P2 p2;
  p2.x0 = x0; p2.a0 = a0;
  p2.wq  = W16;
  p2.wk  = W16 + 32768;
  p2.wvv = W16 + 65536;
  p2.wo  = W16 + 98304;
  p2.w1h = W16 + 131072;
  p2.w2h = W16 + 262144;
  p2.qb = (const float*)d_in[9];  p2.kb = (const float*)d_in[11];
  p2.vb = (const float*)d_in[13]; p2.ob = (const float*)d_in[15];
  p2.n1a = (const float*)d_in[16]; p2.n1b = (const float*)d_in[17];
  p2.n2a = (const float*)d_in[18]; p2.n2b = (const float*)d_in[19];
  p2.b1 = (const float*)d_in[21];  p2.b2 = (const float*)d_in[23];
  p2.fna = (const float*)d_in[24]; p2.fnb = (const float*)d_in[25];
  p2.out_w = (const float*)d_in[26]; p2.out_b = (const float*)d_in[27];
  p2.out = (float*)d_out;
  batchk<<<dim3(256), dim3(512), 0, stream>>>(p2);
}